// Round 14
// baseline (4036.713 us; speedup 1.0000x reference)
//
#include <hip/hip_runtime.h>

typedef unsigned char u8;
typedef unsigned short u16;
typedef unsigned int u32;
typedef unsigned long long u64;
typedef __attribute__((ext_vector_type(4))) int i32x4;
typedef __attribute__((ext_vector_type(4))) float f32x4;

#define SEQ 512

// ---- ws layout (bytes) ----
#define OFF_XBQ  0ull          // 32 MB : xbq [c 128][g 8][hl 2][mt 2][ks 8][lane 64][16] i8
#define OFF_WXQ  33554432ull   //  2 MB : wxq [slot 32][w 2][q 4][ks 8][lane 64][16] i8
#define OFF_WHQ  35651584ull   //  4 MB : whq [slot 32][w 2][q 4][ks 16][lane 64][16] i8
#define OFF_SCL  39845888ull   // 32 KB : scl [part 2][q 4][1024] f32 (0:x, 1:h; = max|col|/127)
#define OFF_SXG  39878656ull   // 128 KB: sxg [tau 512][brow 64] f32 per-token x scale
#define OFF_HIMG 40009728ull   // 512 KB: himg [g 8][grp 2][par 2][ks 16][lane 64][16] i8
                               //         (rows 0-3 = h_hi, rows 8-11 = h_lo; rest unused)
#define OFF_TAG  40534016ull   // 32 KB : tags [g 8][64] u32, 64B stride (1 writer/line)
#define OFF_CTL  40566784ull   // 512 B : xcnt[8] @ g*64

// ---------- helpers ----------
__device__ inline u16 f2bf(float f) {
  u32 u = __float_as_uint(f);
  return (u16)((u + 0x7fffu + ((u >> 16) & 1u)) >> 16);   // RNE
}
__device__ inline float bf2f(u16 u) { return __uint_as_float(((u32)u) << 16); }
__device__ inline float sigm(float x) { return 1.f / (1.f + __expf(-x)); }
__device__ inline float tanh_(float x) { return 1.f - 2.f / (1.f + __expf(2.f * x)); }

#define MFMA_I8(a, b, c_) __builtin_amdgcn_mfma_i32_16x16x64_i8(a, b, c_, 0, 0, 0)

// device(agent)-scope relaxed atomics: bypass L1, serviced at own-XCD L2,
// no cache maintenance (relaxed). Proven r8-r12. (sc0-only asm: falsified r7/r13.)
__device__ inline u32 ald32(const u32* p) {
  return __hip_atomic_load(p, __ATOMIC_RELAXED, __HIP_MEMORY_SCOPE_AGENT);
}
__device__ inline void ast32(u32* p, u32 v) {
  __hip_atomic_store(p, v, __ATOMIC_RELAXED, __HIP_MEMORY_SCOPE_AGENT);
}
__device__ inline i32x4 ald128(const void* p) {
  union { u64 q[2]; i32x4 v; } u;
  u.q[0] = __hip_atomic_load((const u64*)p, __ATOMIC_RELAXED, __HIP_MEMORY_SCOPE_AGENT);
  u.q[1] = __hip_atomic_load((const u64*)p + 1, __ATOMIC_RELAXED, __HIP_MEMORY_SCOPE_AGENT);
  return u.v;
}
#define VMWAIT0() asm volatile("s_waitcnt vmcnt(0)" ::: "memory")
#define CBAR()    asm volatile("" ::: "memory")

// ---------- prep: x -> per-token-scaled i8 hi/lo A-fragment image ----------
__global__ void pack_xq(const float* __restrict__ x, u8* __restrict__ xbq,
                        float* __restrict__ sxg) {
  __shared__ u8 st[1024];
  const int bid = blockIdx.x;           // brow*512 + tau (32768 blocks, 64 thr)
  const int brow = bid >> 9, tau = bid & 511;
  const int lane = threadIdx.x;
  const float* src = x + ((size_t)bid << 9) + lane * 8;
  float4 a = *(const float4*)src;
  float4 b = *(const float4*)(src + 4);
  float v[8] = {a.x, a.y, a.z, a.w, b.x, b.y, b.z, b.w};
  float m = 0.f;
#pragma unroll
  for (int j = 0; j < 8; ++j) m = fmaxf(m, fabsf(v[j]));
#pragma unroll
  for (int i = 1; i < 64; i <<= 1) m = fmaxf(m, __shfl_xor(m, i));
  m = fmaxf(m, 1e-20f);
  const float s = m * (1.f / 127.f), inv = 127.f / m;
#pragma unroll
  for (int j = 0; j < 8; ++j) {
    float t = v[j] * inv;                 // |t| <= 127
    float hi = rintf(t);
    float lo = rintf((t - hi) * 254.f);
    st[lane * 8 + j] = (u8)(signed char)(int)hi;
    st[512 + lane * 8 + j] = (u8)(signed char)(int)lo;
  }
  __syncthreads();
  const int hl = lane >> 5, ks = (lane >> 2) & 7, kg = lane & 3;
  uint4 u = *(const uint4*)&st[hl * 512 + ks * 64 + kg * 16];
  const int c = tau >> 2, tc = tau & 3, g = brow >> 3, rb = brow & 7;
  const int mrow = tc * 8 + rb, mt = mrow >> 4, m15 = mrow & 15;
  *(uint4*)(xbq + (size_t)(((((c * 8 + g) * 2 + hl) * 2 + mt) * 8 + ks) * 64 +
                           kg * 16 + m15) * 16) = u;
  if (lane == 0) sxg[tau * 64 + brow] = s;
}

// ---------- prep: per-gate-column scales ----------
__global__ void calc_scales(const float* __restrict__ W0, const float* __restrict__ W1,
                            const float* __restrict__ W2, const float* __restrict__ W3,
                            float* __restrict__ scl) {
  const int id = blockIdx.x * 256 + threadIdx.x;   // 8192
  const int part = id >> 12, q = (id >> 10) & 3, cc = id & 1023;
  const float* Wg = q == 0 ? W0 : q == 1 ? W1 : q == 2 ? W2 : W3;
  const int r0 = part ? 512 : 0, n = part ? 1024 : 512;
  float mx = 1e-8f;
  for (int k = 0; k < n; ++k) mx = fmaxf(mx, fabsf(Wg[(size_t)(r0 + k) * 1024 + cc]));
  scl[id] = mx * (1.f / 127.f);
}

// ---------- prep: W_h -> i8 B-fragment image (K=1024) ----------
__global__ void pack_whq(const float* __restrict__ W0, const float* __restrict__ W1,
                         const float* __restrict__ W2, const float* __restrict__ W3,
                         const float* __restrict__ scl, u8* __restrict__ whq) {
  const int id = blockIdx.x * 256 + threadIdx.x;    // 262,144 units
  const int lane = id & 63, ks = (id >> 6) & 15, q = (id >> 10) & 3;
  const int w = (id >> 12) & 1, slot = id >> 13;
  const int hcol = slot * 32 + w * 16 + (lane & 15);
  const float* Wg = q == 0 ? W0 : q == 1 ? W1 : q == 2 ? W2 : W3;
  const int k0 = ks * 64 + (lane >> 4) * 16;
  const float inv_s = 1.f / scl[4096 + q * 1024 + hcol];
  u8 tmp[16];
#pragma unroll
  for (int j = 0; j < 16; ++j) {
    float v = Wg[(size_t)(512 + k0 + j) * 1024 + hcol] * inv_s;
    tmp[j] = (u8)(signed char)(int)rintf(fminf(fmaxf(v, -127.f), 127.f));
  }
  *(uint4*)(whq + (size_t)id * 16) = *(uint4*)tmp;
}

// ---------- prep: W_x -> i8 B-fragment image (K=512) ----------
__global__ void pack_wxq(const float* __restrict__ W0, const float* __restrict__ W1,
                         const float* __restrict__ W2, const float* __restrict__ W3,
                         const float* __restrict__ scl, u8* __restrict__ wxq) {
  const int id = blockIdx.x * 256 + threadIdx.x;    // 131,072 units
  const int lane = id & 63, ks = (id >> 6) & 7, q = (id >> 9) & 3;
  const int w = (id >> 11) & 1, slot = id >> 12;
  const int hcol = slot * 32 + w * 16 + (lane & 15);
  const float* Wg = q == 0 ? W0 : q == 1 ? W1 : q == 2 ? W2 : W3;
  const int k0 = ks * 64 + (lane >> 4) * 16;
  const float inv_s = 1.f / scl[q * 1024 + hcol];
  u8 tmp[16];
#pragma unroll
  for (int j = 0; j < 16; ++j) {
    float v = Wg[(size_t)(k0 + j) * 1024 + hcol] * inv_s;
    tmp[j] = (u8)(signed char)(int)rintf(fminf(fmaxf(v, -127.f), 127.f));
  }
  *(uint4*)(wxq + (size_t)id * 16) = *(uint4*)tmp;
}

// ---------- main persistent kernel ----------
// 256 blocks x 192 thr (3 waves). group g = XCD id; slot via L2 atomic; 1 block/CU
// by LDS pigeonhole. TWO independent 4-row recurrences per XCD (A: rows 0-3,
// B: rows 4-7), alternated within each consumer wave so each group's
// publish->discovery latency hides under the other group's compute.
// Tag per wave: 2t-1 after A(t), 2t after B(t). W_h i8 in LDS; A-tiles = packed
// hi(rows0-3)/lo(rows8-11) i8 in own-XCD L2; shfl_xor(32) recombine. Producer
// (wave 2): gates_x -> 2-chunk LDS ring. Agent atomics only; no fences.
__global__ void __launch_bounds__(192, 1) lstm_main(
    char* __restrict__ ws,
    const float* __restrict__ b_i, const float* __restrict__ b_f,
    const float* __restrict__ b_c, const float* __restrict__ b_o,
    const float* __restrict__ fcw, const float* __restrict__ fcb,
    float* __restrict__ out) {
  __shared__ __align__(16) u8 wh[131072];      // [w 2][q 4][ks 16][lane 64][16] i8
  __shared__ __align__(16) u16 ring_[8192];    // 16KB [par 2][tc 4][cc 128][rb 8] bf16
  __shared__ __align__(16) u8 pub_[512];       // [w 2][line 16][col 16] i8
  __shared__ u32 flg[16];                      // 0:slot 1:pc 2,3:ct[w]

  const int tid = threadIdx.x;
  const int wid = tid >> 6;
  const int lane = tid & 63;
  const int kgrp = lane >> 4;
  const int l15 = lane & 15;

  u32 xcd;
  asm volatile("s_getreg_b32 %0, hwreg(HW_REG_XCC_ID, 0, 8)" : "=s"(xcd));
  const int g = (int)(xcd & 7);

  if (tid == 0) {
    u32 s = __hip_atomic_fetch_add((u32*)(ws + OFF_CTL) + g * 16, 1u,
                                   __ATOMIC_RELAXED, __HIP_MEMORY_SCOPE_SYSTEM);
    flg[0] = s; flg[1] = 0; flg[2] = 0; flg[3] = 0;
  }
  __syncthreads();
  const int slot = (int)flg[0];
  if (slot >= 32) return;   // cannot happen (1 block/CU pigeonhole)

  u8* himg = (u8*)(ws + OFF_HIMG) + (size_t)g * 65536;   // [grp 2][par 2][16KB]
  u32* tags = (u32*)(ws + OFF_TAG) + g * 1024;           // 64 tags @ 64B stride
  const float* scl = (const float*)(ws + OFF_SCL);

  // one-time W_h LDS fill (8192 x 16B units, 192 threads)
  {
    const u8* src = (const u8*)(ws + OFF_WHQ) + (size_t)slot * 131072;
    for (int i = 0; i < 43; ++i) {
      int u = i * 192 + tid;
      if (u < 8192) *(uint4*)&wh[u * 16] = *(const uint4*)(src + u * 16);
    }
  }
  __syncthreads();

  if (wid == 2) {
    // ================= producer wave: gates_x -> LDS ring =================
    const u8* xq = (const u8*)(ws + OFF_XBQ);
    const u8* wxs = (const u8*)(ws + OFF_WXQ) + (size_t)slot * 65536;
    const float* sxg = (const float*)(ws + OFF_SXG);
    float swx[2][4], bs[2][4];
#pragma unroll
    for (int w2 = 0; w2 < 2; ++w2) {
      const int cwq = slot * 32 + w2 * 16 + l15;
#pragma unroll
      for (int q = 0; q < 4; ++q) swx[w2][q] = scl[q * 1024 + cwq];
      bs[w2][0] = b_i[cwq]; bs[w2][1] = b_f[cwq];
      bs[w2][2] = b_c[cwq]; bs[w2][3] = b_o[cwq];
    }
    for (int c = 0; c < 128; ++c) {
      if (c >= 2) {
        const u32 need = (u32)(4 * c - 4);
        while (((volatile u32*)flg)[2] < need || ((volatile u32*)flg)[3] < need) {}
        CBAR();
      }
      float sxv[2][4];
#pragma unroll
      for (int mt = 0; mt < 2; ++mt)
#pragma unroll
        for (int r = 0; r < 4; ++r)
          sxv[mt][r] = sxg[(c * 4 + mt * 2 + (kgrp >> 1)) * 64 + g * 8 + (kgrp & 1) * 4 + r];
      i32x4 accH[2][2][4], accL[2][2][4];
#pragma unroll
      for (int mt = 0; mt < 2; ++mt)
#pragma unroll
        for (int w2 = 0; w2 < 2; ++w2)
#pragma unroll
          for (int q = 0; q < 4; ++q) {
            accH[mt][w2][q] = (i32x4){0, 0, 0, 0};
            accL[mt][w2][q] = (i32x4){0, 0, 0, 0};
          }
      const u8* xc = xq + (size_t)(c * 8 + g) * 32768;
#pragma unroll 2
      for (int ks = 0; ks < 8; ++ks) {
        i32x4 aH0 = *(const i32x4*)(xc + (size_t)((0 * 2 + 0) * 8 + ks) * 1024 + lane * 16);
        i32x4 aH1 = *(const i32x4*)(xc + (size_t)((0 * 2 + 1) * 8 + ks) * 1024 + lane * 16);
        i32x4 aL0 = *(const i32x4*)(xc + (size_t)((1 * 2 + 0) * 8 + ks) * 1024 + lane * 16);
        i32x4 aL1 = *(const i32x4*)(xc + (size_t)((1 * 2 + 1) * 8 + ks) * 1024 + lane * 16);
#pragma unroll
        for (int w2 = 0; w2 < 2; ++w2)
#pragma unroll
          for (int q = 0; q < 4; ++q) {
            i32x4 b = *(const i32x4*)(wxs + (size_t)(((w2 * 4 + q) * 8 + ks) * 64 + lane) * 16);
            accH[0][w2][q] = MFMA_I8(aH0, b, accH[0][w2][q]);
            accH[1][w2][q] = MFMA_I8(aH1, b, accH[1][w2][q]);
            accL[0][w2][q] = MFMA_I8(aL0, b, accL[0][w2][q]);
            accL[1][w2][q] = MFMA_I8(aL1, b, accL[1][w2][q]);
          }
      }
#pragma unroll
      for (int mt = 0; mt < 2; ++mt)
#pragma unroll
        for (int w2 = 0; w2 < 2; ++w2)
#pragma unroll
          for (int q = 0; q < 4; ++q) {
            u64 pk = 0;
#pragma unroll
            for (int r = 0; r < 4; ++r) {
              float val = sxv[mt][r] * swx[w2][q] *
                          ((float)accH[mt][w2][q][r] + (float)accL[mt][w2][q][r] * (1.f / 254.f)) +
                          bs[w2][q];
              pk |= (u64)f2bf(val) << (16 * r);
            }
            const int tc = mt * 2 + (kgrp >> 1);
            const int cc2 = (w2 * 4 + q) * 16 + l15;
            const int rb0 = (kgrp & 1) * 4;
            *(u64*)&ring_[(((c & 1) * 4 + tc) * 128 + cc2) * 8 + rb0] = pk;
          }
      asm volatile("s_waitcnt lgkmcnt(0)" ::: "memory");
      ((volatile u32*)flg)[1] = (u32)(c + 1);
    }
    return;
  }

  // ================= consumer waves (w = wid in {0,1}) =================
  const int w = wid;
  const int col = slot * 32 + w * 16 + l15;
  const int idx = slot * 2 + w;              // publish tile id
  float sA[4];
#pragma unroll
  for (int q = 0; q < 4; ++q) sA[q] = scl[4096 + q * 1024 + col] * (1.f / 127.f);

  float csA[4] = {0.f, 0.f, 0.f, 0.f};       // group A cell state (kgrp==0, rows 0-3)
  float csB[4] = {0.f, 0.f, 0.f, 0.f};       // group B cell state (kgrp==0, rows 4-7)
  u32* mytag = tags + idx * 16;
  const u32* mypoll = tags + lane * 16;      // lane-parallel: tag[lane]

  // one phase of group G (0=A rows 0-3, 1=B rows 4-7) at period t
#define PHASE(G, CS)                                                           \
  {                                                                            \
    const int tau = t - 1, tc = tau & 3, ch = tau >> 2;                        \
    while (((volatile u32*)flg)[1] <= (u32)ch) {}                              \
    CBAR();                                                                    \
    f32x4 gx[4];                                                               \
    _Pragma("unroll") for (int q = 0; q < 4; ++q) {                            \
      u64 pk = *(const u64*)&ring_[(((ch & 1) * 4 + tc) * 128 +                \
                                    (w * 4 + q) * 16 + l15) * 8 + (G) * 4];    \
      gx[q][0] = bf2f((u16)pk);         gx[q][1] = bf2f((u16)(pk >> 16));      \
      gx[q][2] = bf2f((u16)(pk >> 32)); gx[q][3] = bf2f((u16)(pk >> 48));      \
    }                                                                          \
    const u8* ab = himg + (G) * 32768 + (tau & 1) * 16384 + lane * 16;         \
    const int thr = 2 * t - 3 + (G);                                           \
    u64 rbal = __ballot((int)ald32(mypoll) >= thr);                            \
    i32x4 A[16];                                                               \
    i32x4 acc[4];                                                              \
    _Pragma("unroll") for (int q = 0; q < 4; ++q) acc[q] = (i32x4){0, 0, 0, 0};\
    _Pragma("unroll") for (int q4 = 0; q4 < 4; ++q4) {                         \
      if (thr > 0) {                                                           \
        const u64 need = 0xFFFFull << (q4 * 16);                               \
        while ((rbal & need) != need)                                          \
          rbal = __ballot((int)ald32(mypoll) >= thr);                          \
        CBAR();                                                                \
      }                                                                        \
      _Pragma("unroll") for (int k4 = 0; k4 < 4; ++k4)                         \
        A[q4 * 4 + k4] = ald128(ab + (size_t)(q4 * 4 + k4) * 1024);            \
      if (q4 > 0) {                                                            \
        _Pragma("unroll") for (int k4 = 0; k4 < 4; ++k4) {                     \
          const int ks = (q4 - 1) * 4 + k4;                                    \
          _Pragma("unroll") for (int q = 0; q < 4; ++q) {                      \
            i32x4 b = *(const i32x4*)&wh[(size_t)(((w * 4 + q) * 16 + ks) * 64 \
                                                  + lane) * 16];               \
            acc[q] = MFMA_I8(A[ks], b, acc[q]);                                \
          }                                                                    \
        }                                                                      \
      }                                                                        \
    }                                                                          \
    _Pragma("unroll") for (int k4 = 0; k4 < 4; ++k4) {                         \
      const int ks = 12 + k4;                                                  \
      _Pragma("unroll") for (int q = 0; q < 4; ++q) {                          \
        i32x4 b = *(const i32x4*)&wh[(size_t)(((w * 4 + q) * 16 + ks) * 64     \
                                              + lane) * 16];                   \
        acc[q] = MFMA_I8(A[ks], b, acc[q]);                                    \
      }                                                                        \
    }                                                                          \
    _Pragma("unroll") for (int r = 0; r < 4; ++r) {                            \
      float p[4];                                                              \
      _Pragma("unroll") for (int q = 0; q < 4; ++q) {                          \
        float hiF = (float)acc[q][r];                                          \
        float loF = (float)__shfl_xor(acc[q][r], 32);                          \
        p[q] = fmaf(sA[q], fmaf(loF, 1.f / 254.f, hiF), gx[q][r]);             \
      }                                                                        \
      float iv = sigm(p[0]), fv = sigm(p[1]), gv = tanh_(p[2]), ov = sigm(p[3]);\
      float cn = fv * CS[r] + iv * gv;                                         \
      CS[r] = cn;                                                              \
      float h = ov * tanh_(cn);                                                \
      float hq = h * 127.f;                                                    \
      float hi = rintf(hq);                                                    \
      float lo = rintf((hq - hi) * 254.f);                                     \
      if (kgrp == 0) {                                                         \
        pub_[w * 256 + r * 16 + l15] = (u8)(signed char)(int)hi;               \
        pub_[w * 256 + (8 + r) * 16 + l15] = (u8)(signed char)(int)lo;         \
      }                                                                        \
    }                                                                          \
    asm volatile("s_waitcnt lgkmcnt(0)" ::: "memory");                         \
    if ((lane & 7) < 4 && lane < 12) {                                         \
      uint4 v = *(const uint4*)&pub_[w * 256 + lane * 16];                     \
      u8* dst = himg + (G) * 32768 + (size_t)((t & 1) * 16384) +               \
                (size_t)(((idx >> 2) * 64 + (idx & 3) * 16 + lane) * 16);      \
      *(uint4*)dst = v;                                                        \
    }                                                                          \
    VMWAIT0();                                                                 \
    if (lane == 0) ast32(mytag, (u32)(2 * t - 1 + (G)));                       \
  }

  for (int t = 1; t <= SEQ; ++t) {
    PHASE(0, csA);
    PHASE(1, csB);
    ((volatile u32*)flg)[2 + w] = (u32)t;
  }
#undef PHASE

  // ================= FC epilogue (h_512: both groups, parity 0) =================
  { u32 tv; do { tv = ald32(tags + lane * 16); } while (!__all(tv >= (u32)(2 * SEQ))); }
  CBAR();
  {
    const int row = tid >> 4, c16 = tid & 15;   // tid 0-127: rows 0-7
    const int grp = row >> 2, lr = row & 3;
    const u8* hb = himg + grp * 32768;          // parity 0
    const int ocol = slot * 16 + c16;
    const float* wr = fcw + (size_t)ocol * 1024;
    float acc = fcb[ocol];
    const float C1 = 1.f / 127.f, C2 = 1.f / 32258.f;
    for (int ks = 0; ks < 16; ++ks) {
#pragma unroll
      for (int kg = 0; kg < 4; ++kg) {
        union { i32x4 v; signed char b[16]; } H, L;
        H.v = ald128(hb + (size_t)((ks * 64 + kg * 16 + lr) * 16));
        L.v = ald128(hb + (size_t)((ks * 64 + kg * 16 + 8 + lr) * 16));
        const float* wp = wr + ks * 64 + kg * 16;
#pragma unroll
        for (int j = 0; j < 16; ++j)
          acc += ((float)H.b[j] * C1 + (float)L.b[j] * C2) * wp[j];
      }
    }
    out[(size_t)(g * 8 + row) * 512 + ocol] = acc;
  }
}

// ---------- launch ----------
extern "C" void kernel_launch(void* const* d_in, const int* in_sizes, int n_in,
                              void* d_out, int out_size, void* d_ws, size_t ws_size,
                              hipStream_t stream) {
  const float* x  = (const float*)d_in[0];
  const float* W0 = (const float*)d_in[1];
  const float* W1 = (const float*)d_in[2];
  const float* W2 = (const float*)d_in[3];
  const float* W3 = (const float*)d_in[4];
  const float* bi = (const float*)d_in[5];
  const float* bf = (const float*)d_in[6];
  const float* bc = (const float*)d_in[7];
  const float* bo = (const float*)d_in[8];
  const float* fcw = (const float*)d_in[9];
  const float* fcb = (const float*)d_in[10];
  float* out = (float*)d_out;

  char* ws = (char*)d_ws;
  pack_xq<<<dim3(32768), dim3(64), 0, stream>>>(x, (u8*)(ws + OFF_XBQ),
                                                (float*)(ws + OFF_SXG));
  calc_scales<<<dim3(32), dim3(256), 0, stream>>>(W0, W1, W2, W3, (float*)(ws + OFF_SCL));
  pack_whq<<<dim3(1024), dim3(256), 0, stream>>>(W0, W1, W2, W3,
                                                 (const float*)(ws + OFF_SCL),
                                                 (u8*)(ws + OFF_WHQ));
  pack_wxq<<<dim3(512), dim3(256), 0, stream>>>(W0, W1, W2, W3,
                                                (const float*)(ws + OFF_SCL),
                                                (u8*)(ws + OFF_WXQ));
  // zero himg + tags + ctl (contiguous: 524288 + 32768 + 512)
  hipMemsetAsync(ws + OFF_HIMG, 0, 524288 + 32768 + 512, stream);
  lstm_main<<<dim3(256), dim3(192), 0, stream>>>(ws, bi, bf, bc, bo, fcw, fcb, out);
}

// Round 15
// 2578.044 us; speedup vs baseline: 1.5658x; 1.5658x over previous
//
#include <hip/hip_runtime.h>

typedef unsigned char u8;
typedef unsigned short u16;
typedef unsigned int u32;
typedef unsigned long long u64;
typedef int i32;
typedef __attribute__((ext_vector_type(4))) int i32x4;
typedef __attribute__((ext_vector_type(4))) float f32x4;

#define SEQ 512

// ---- ws layout (bytes) ----
#define OFF_XBQ  0ull          // 32 MB : xbq [c 128][g 8][hl 2][mt 2][ks 8][lane 64][16] i8
#define OFF_WXQ  33554432ull   //  2 MB : wxq [slot 64][q 4][ks 8][lane 64][16] i8
#define OFF_WHQ  35651584ull   //  4 MB : whq [slot 64][q 4][ks 16][lane 64][16] i8
#define OFF_SCL  39845888ull   // 32 KB : scl [part 2][q 4][1024] f32 (0:x, 1:h; = max|col|/127)
#define OFF_SXG  39878656ull   // 128 KB: sxg [tau 512][brow 64] f32 per-token x scale
#define OFF_HIMG 40009728ull   // 256 KB: himg [g 8][par 2][ks 16][lane 64][16] i8
                               //         (A rows 0-7 = h_hi, rows 8-15 = h_lo)
#define OFF_TAG  40271872ull   // 32 KB : tags [g 8][64] u32, 64B stride (1 writer/line)
#define OFF_CTL  40304640ull   //  1 KB : xcnt[8] @ g*64

// ---------- helpers ----------
__device__ inline u16 f2bf(float f) {
  u32 u = __float_as_uint(f);
  return (u16)((u + 0x7fffu + ((u >> 16) & 1u)) >> 16);   // RNE
}
__device__ inline float bf2f(u16 u) { return __uint_as_float(((u32)u) << 16); }
__device__ inline float sigm(float x) { return 1.f / (1.f + __expf(-x)); }
__device__ inline float tanh_(float x) { return 1.f - 2.f / (1.f + __expf(2.f * x)); }

#define MFMA_I8(a, b, c_) __builtin_amdgcn_mfma_i32_16x16x64_i8(a, b, c_, 0, 0, 0)

// device(agent)-scope relaxed atomics: bypass L1, serviced coherently,
// no cache maintenance (relaxed). Proven r8-r12. (sc0-only asm: falsified r7/r13.)
__device__ inline u32 ald32(const u32* p) {
  return __hip_atomic_load(p, __ATOMIC_RELAXED, __HIP_MEMORY_SCOPE_AGENT);
}
__device__ inline void ast32(u32* p, u32 v) {
  __hip_atomic_store(p, v, __ATOMIC_RELAXED, __HIP_MEMORY_SCOPE_AGENT);
}
__device__ inline i32x4 ald128(const void* p) {
  union { u64 q[2]; i32x4 v; } u;
  u.q[0] = __hip_atomic_load((const u64*)p, __ATOMIC_RELAXED, __HIP_MEMORY_SCOPE_AGENT);
  u.q[1] = __hip_atomic_load((const u64*)p + 1, __ATOMIC_RELAXED, __HIP_MEMORY_SCOPE_AGENT);
  return u.v;
}
#define VMWAIT0() asm volatile("s_waitcnt vmcnt(0)" ::: "memory")
#define CBAR()    asm volatile("" ::: "memory")

// ---------- prep: x -> per-token-scaled i8 hi/lo A-fragment image ----------
__global__ void pack_xq(const float* __restrict__ x, u8* __restrict__ xbq,
                        float* __restrict__ sxg) {
  __shared__ u8 st[1024];
  const int bid = blockIdx.x;           // brow*512 + tau (32768 blocks, 64 thr)
  const int brow = bid >> 9, tau = bid & 511;
  const int lane = threadIdx.x;
  const float* src = x + ((size_t)bid << 9) + lane * 8;
  float4 a = *(const float4*)src;
  float4 b = *(const float4*)(src + 4);
  float v[8] = {a.x, a.y, a.z, a.w, b.x, b.y, b.z, b.w};
  float m = 0.f;
#pragma unroll
  for (int j = 0; j < 8; ++j) m = fmaxf(m, fabsf(v[j]));
#pragma unroll
  for (int i = 1; i < 64; i <<= 1) m = fmaxf(m, __shfl_xor(m, i));
  m = fmaxf(m, 1e-20f);
  const float s = m * (1.f / 127.f), inv = 127.f / m;
#pragma unroll
  for (int j = 0; j < 8; ++j) {
    float t = v[j] * inv;                 // |t| <= 127
    float hi = rintf(t);
    float lo = rintf((t - hi) * 254.f);
    st[lane * 8 + j] = (u8)(signed char)(int)hi;
    st[512 + lane * 8 + j] = (u8)(signed char)(int)lo;
  }
  __syncthreads();
  const int hl = lane >> 5, ks = (lane >> 2) & 7, kg = lane & 3;
  uint4 u = *(const uint4*)&st[hl * 512 + ks * 64 + kg * 16];
  const int c = tau >> 2, tc = tau & 3, g = brow >> 3, rb = brow & 7;
  const int mrow = tc * 8 + rb, mt = mrow >> 4, m15 = mrow & 15;
  *(uint4*)(xbq + (size_t)(((((c * 8 + g) * 2 + hl) * 2 + mt) * 8 + ks) * 64 +
                           kg * 16 + m15) * 16) = u;
  if (lane == 0) sxg[tau * 64 + brow] = s;
}

// ---------- prep: per-gate-column scales ----------
__global__ void calc_scales(const float* __restrict__ W0, const float* __restrict__ W1,
                            const float* __restrict__ W2, const float* __restrict__ W3,
                            float* __restrict__ scl) {
  const int id = blockIdx.x * 256 + threadIdx.x;   // 8192
  const int part = id >> 12, q = (id >> 10) & 3, cc = id & 1023;
  const float* Wg = q == 0 ? W0 : q == 1 ? W1 : q == 2 ? W2 : W3;
  const int r0 = part ? 512 : 0, n = part ? 1024 : 512;
  float mx = 1e-8f;
  for (int k = 0; k < n; ++k) mx = fmaxf(mx, fabsf(Wg[(size_t)(r0 + k) * 1024 + cc]));
  scl[id] = mx * (1.f / 127.f);
}

// ---------- prep: W_h -> i8 B-fragment image (K=1024, 64 slots x 16 cols) ----------
__global__ void pack_whq(const float* __restrict__ W0, const float* __restrict__ W1,
                         const float* __restrict__ W2, const float* __restrict__ W3,
                         const float* __restrict__ scl, u8* __restrict__ whq) {
  const int id = blockIdx.x * 256 + threadIdx.x;    // 262,144 units
  const int lane = id & 63, ks = (id >> 6) & 15, q = (id >> 10) & 3;
  const int slot = id >> 12;
  const int hcol = slot * 16 + (lane & 15);
  const float* Wg = q == 0 ? W0 : q == 1 ? W1 : q == 2 ? W2 : W3;
  const int k0 = ks * 64 + (lane >> 4) * 16;
  const float inv_s = 1.f / scl[4096 + q * 1024 + hcol];
  u8 tmp[16];
#pragma unroll
  for (int j = 0; j < 16; ++j) {
    float v = Wg[(size_t)(512 + k0 + j) * 1024 + hcol] * inv_s;
    tmp[j] = (u8)(signed char)(int)rintf(fminf(fmaxf(v, -127.f), 127.f));
  }
  *(uint4*)(whq + (size_t)id * 16) = *(uint4*)tmp;
}

// ---------- prep: W_x -> i8 B-fragment image (K=512, 64 slots x 16 cols) ----------
__global__ void pack_wxq(const float* __restrict__ W0, const float* __restrict__ W1,
                         const float* __restrict__ W2, const float* __restrict__ W3,
                         const float* __restrict__ scl, u8* __restrict__ wxq) {
  const int id = blockIdx.x * 256 + threadIdx.x;    // 131,072 units
  const int lane = id & 63, ks = (id >> 6) & 7, q = (id >> 9) & 3;
  const int slot = id >> 11;
  const int hcol = slot * 16 + (lane & 15);
  const float* Wg = q == 0 ? W0 : q == 1 ? W1 : q == 2 ? W2 : W3;
  const int k0 = ks * 64 + (lane >> 4) * 16;
  const float inv_s = 1.f / scl[q * 1024 + hcol];
  u8 tmp[16];
#pragma unroll
  for (int j = 0; j < 16; ++j) {
    float v = Wg[(size_t)(k0 + j) * 1024 + hcol] * inv_s;
    tmp[j] = (u8)(signed char)(int)rintf(fminf(fmaxf(v, -127.f), 127.f));
  }
  *(uint4*)(wxq + (size_t)id * 16) = *(uint4*)tmp;
}

// ---------- main persistent kernel ----------
// 512 blocks x 192 thr; 2 blocks/CU (78.1KB LDS pigeonhole) -> 6 waves/CU TLP.
// group g = XCD id; 64 slots/XCD x 16 h-cols. Consumer waves K-SPLIT the h-GEMM:
// w0 = k-tiles 0-7, w1 = 8-15 (8KB loads, 32 MFMA each); w1 posts i32 partials
// to LDS; w0 combines + gates + publish + tag, w1 races ahead to next step.
// Quarter-gated ballot polls per half. Producer (wave 2): gates_x -> LDS ring.
__global__ void __launch_bounds__(192, 2) lstm_main(
    char* __restrict__ ws,
    const float* __restrict__ b_i, const float* __restrict__ b_f,
    const float* __restrict__ b_c, const float* __restrict__ b_o,
    const float* __restrict__ fcw, const float* __restrict__ fcb,
    float* __restrict__ out) {
  __shared__ __align__(16) u8 wh[65536];       // [q 4][ks 16][lane 64][16] i8
  __shared__ __align__(16) u16 ring_[4096];    // 8KB [par 2][tc 4][cc 64][rb 8] bf16
  __shared__ __align__(16) i32 cmb_[1024];     // 4KB [lane 64][q 4][4] i32 partials
  __shared__ __align__(16) u8 pub_[256];       // [line 16][col 16] i8
  __shared__ u32 flg[16];                      // 0:slot 1:pc 2,3:ct[w] 4:cmb-flag

  const int tid = threadIdx.x;
  const int wid = tid >> 6;
  const int lane = tid & 63;
  const int kgrp = lane >> 4;
  const int l15 = lane & 15;

  u32 xcd;
  asm volatile("s_getreg_b32 %0, hwreg(HW_REG_XCC_ID, 0, 8)" : "=s"(xcd));
  const int g = (int)(xcd & 7);

  if (tid == 0) {
    u32 s = __hip_atomic_fetch_add((u32*)(ws + OFF_CTL) + g * 16, 1u,
                                   __ATOMIC_RELAXED, __HIP_MEMORY_SCOPE_SYSTEM);
    flg[0] = s; flg[1] = 0; flg[2] = 0; flg[3] = 0; flg[4] = 0;
  }
  __syncthreads();
  const int slot = (int)flg[0];
  if (slot >= 64) return;   // cannot happen (2 blocks/CU pigeonhole, 64/XCD)

  u8* himg = (u8*)(ws + OFF_HIMG) + (size_t)g * 32768;
  u32* tags = (u32*)(ws + OFF_TAG) + g * 1024;   // 64 tags @ 64B stride
  const float* scl = (const float*)(ws + OFF_SCL);

  // one-time W_h LDS fill (4096 x 16B units, 192 threads)
  {
    const u8* src = (const u8*)(ws + OFF_WHQ) + (size_t)slot * 65536;
    for (int i = 0; i < 22; ++i) {
      int u = i * 192 + tid;
      if (u < 4096) *(uint4*)&wh[u * 16] = *(const uint4*)(src + u * 16);
    }
  }
  __syncthreads();

  if (wid == 2) {
    // ================= producer wave: gates_x -> LDS ring =================
    const u8* xq = (const u8*)(ws + OFF_XBQ);
    const u8* wxs = (const u8*)(ws + OFF_WXQ) + (size_t)slot * 32768;
    const float* sxg = (const float*)(ws + OFF_SXG);
    float swx[4], bs[4];
    {
      const int cwq = slot * 16 + l15;
#pragma unroll
      for (int q = 0; q < 4; ++q) swx[q] = scl[q * 1024 + cwq];
      bs[0] = b_i[cwq]; bs[1] = b_f[cwq]; bs[2] = b_c[cwq]; bs[3] = b_o[cwq];
    }
    for (int c = 0; c < 128; ++c) {
      if (c >= 2) {
        const u32 need = (u32)(4 * c - 4);
        while (((volatile u32*)flg)[2] < need || ((volatile u32*)flg)[3] < need) {}
        CBAR();
      }
      float sxv[2][4];
#pragma unroll
      for (int mt = 0; mt < 2; ++mt)
#pragma unroll
        for (int r = 0; r < 4; ++r)
          sxv[mt][r] = sxg[(c * 4 + mt * 2 + (kgrp >> 1)) * 64 + g * 8 + (kgrp & 1) * 4 + r];
      i32x4 accH[2][4], accL[2][4];
#pragma unroll
      for (int mt = 0; mt < 2; ++mt)
#pragma unroll
        for (int q = 0; q < 4; ++q) {
          accH[mt][q] = (i32x4){0, 0, 0, 0};
          accL[mt][q] = (i32x4){0, 0, 0, 0};
        }
      const u8* xc = xq + (size_t)(c * 8 + g) * 32768;
#pragma unroll 2
      for (int ks = 0; ks < 8; ++ks) {
        i32x4 aH0 = *(const i32x4*)(xc + (size_t)((0 * 2 + 0) * 8 + ks) * 1024 + lane * 16);
        i32x4 aH1 = *(const i32x4*)(xc + (size_t)((0 * 2 + 1) * 8 + ks) * 1024 + lane * 16);
        i32x4 aL0 = *(const i32x4*)(xc + (size_t)((1 * 2 + 0) * 8 + ks) * 1024 + lane * 16);
        i32x4 aL1 = *(const i32x4*)(xc + (size_t)((1 * 2 + 1) * 8 + ks) * 1024 + lane * 16);
#pragma unroll
        for (int q = 0; q < 4; ++q) {
          i32x4 b = *(const i32x4*)(wxs + (size_t)((q * 8 + ks) * 64 + lane) * 16);
          accH[0][q] = MFMA_I8(aH0, b, accH[0][q]);
          accH[1][q] = MFMA_I8(aH1, b, accH[1][q]);
          accL[0][q] = MFMA_I8(aL0, b, accL[0][q]);
          accL[1][q] = MFMA_I8(aL1, b, accL[1][q]);
        }
      }
#pragma unroll
      for (int mt = 0; mt < 2; ++mt)
#pragma unroll
        for (int q = 0; q < 4; ++q) {
          u64 pk = 0;
#pragma unroll
          for (int r = 0; r < 4; ++r) {
            float val = sxv[mt][r] * swx[q] *
                        ((float)accH[mt][q][r] + (float)accL[mt][q][r] * (1.f / 254.f)) +
                        bs[q];
            pk |= (u64)f2bf(val) << (16 * r);
          }
          const int tc = mt * 2 + (kgrp >> 1);
          const int cc = q * 16 + l15;
          const int rb0 = (kgrp & 1) * 4;
          *(u64*)&ring_[(((c & 1) * 4 + tc) * 64 + cc) * 8 + rb0] = pk;
        }
      asm volatile("s_waitcnt lgkmcnt(0)" ::: "memory");
      ((volatile u32*)flg)[1] = (u32)(c + 1);
    }
    return;
  }

  // ================= consumer waves: K-split (w0: ks 0-7, w1: ks 8-15) ==========
  const int w = wid;
  const int col = slot * 16 + l15;
  float sA[4];
#pragma unroll
  for (int q = 0; q < 4; ++q) sA[q] = scl[4096 + q * 1024 + col] * (1.f / 127.f);

  float cs[4] = {0.f, 0.f, 0.f, 0.f};
  u32* mytag = tags + slot * 16;
  const u32* mypoll = tags + lane * 16;      // lane-parallel: tag[lane]
  const int rbb = (kgrp & 1) * 4;

  for (int t = 1; t <= SEQ; ++t) {
    const int tau = t - 1, ch = tau >> 2, tc = tau & 3, par = tau & 1;
    f32x4 gx[4];
    if (w == 0) {
      // gates_x from LDS ring (w0 only)
      while (((volatile u32*)flg)[1] <= (u32)ch) {}
      CBAR();
#pragma unroll
      for (int q = 0; q < 4; ++q) {
        u64 pk = *(const u64*)&ring_[(((ch & 1) * 4 + tc) * 64 + q * 16 + l15) * 8 + rbb];
        gx[q][0] = bf2f((u16)pk);         gx[q][1] = bf2f((u16)(pk >> 16));
        gx[q][2] = bf2f((u16)(pk >> 32)); gx[q][3] = bf2f((u16)(pk >> 48));
      }
    }
    // ---- half-gated poll -> load -> MFMA on this wave's 8 k-tiles ----
    const u8* ab = himg + par * 16384 + lane * 16;
    u64 rbal = 0;
    if (tau > 0) rbal = __ballot(ald32(mypoll) >= (u32)tau);
    i32x4 A[8];
    i32x4 acc[4];
#pragma unroll
    for (int q = 0; q < 4; ++q) acc[q] = (i32x4){0, 0, 0, 0};
#pragma unroll
    for (int h2 = 0; h2 < 2; ++h2) {
      if (tau > 0) {
        const u64 need = 0xFFFFull << ((w * 2 + h2) * 16);
        while ((rbal & need) != need)
          rbal = __ballot(ald32(mypoll) >= (u32)tau);
        CBAR();
      }
#pragma unroll
      for (int k4 = 0; k4 < 4; ++k4)
        A[h2 * 4 + k4] = ald128(ab + (size_t)(w * 8 + h2 * 4 + k4) * 1024);
      if (h2 == 1) {
#pragma unroll
        for (int k4 = 0; k4 < 4; ++k4) {
          const int ks = w * 8 + k4;
#pragma unroll
          for (int q = 0; q < 4; ++q) {
            i32x4 b = *(const i32x4*)&wh[(size_t)(((q * 16 + ks) * 64 + lane)) * 16];
            acc[q] = MFMA_I8(A[k4], b, acc[q]);
          }
        }
      }
    }
#pragma unroll
    for (int k4 = 0; k4 < 4; ++k4) {
      const int ks = w * 8 + 4 + k4;
#pragma unroll
      for (int q = 0; q < 4; ++q) {
        i32x4 b = *(const i32x4*)&wh[(size_t)(((q * 16 + ks) * 64 + lane)) * 16];
        acc[q] = MFMA_I8(A[4 + k4], b, acc[q]);
      }
    }
    if (w == 1) {
      // post partials to w0 and race ahead to next step
#pragma unroll
      for (int q = 0; q < 4; ++q)
        *((i32x4*)cmb_ + lane * 4 + q) = acc[q];
      asm volatile("s_waitcnt lgkmcnt(0)" ::: "memory");
      ((volatile u32*)flg)[4] = (u32)t;
      ((volatile u32*)flg)[3] = (u32)t;
      continue;
    }
    // ---- w0: combine partials, gates, cell state, quantize, publish ----
    while (((volatile u32*)flg)[4] < (u32)t) {}
    CBAR();
#pragma unroll
    for (int q = 0; q < 4; ++q) {
      i32x4 o = *((const i32x4*)cmb_ + lane * 4 + q);
      acc[q][0] += o[0]; acc[q][1] += o[1]; acc[q][2] += o[2]; acc[q][3] += o[3];
    }
#pragma unroll
    for (int r = 0; r < 4; ++r) {
      float p[4];
#pragma unroll
      for (int q = 0; q < 4; ++q) {
        float hiF = (float)acc[q][r];
        float loF = (float)__shfl_xor(acc[q][r], 32);
        p[q] = fmaf(sA[q], fmaf(loF, 1.f / 254.f, hiF), gx[q][r]);
      }
      float iv = sigm(p[0]), fv = sigm(p[1]), gv = tanh_(p[2]), ov = sigm(p[3]);
      float cn = fv * cs[r] + iv * gv;
      cs[r] = cn;
      float h = ov * tanh_(cn);
      float hq = h * 127.f;
      float hi = rintf(hq);
      float lo = rintf((hq - hi) * 254.f);
      if (kgrp < 2) {
        const int rr = kgrp * 4 + r;
        pub_[rr * 16 + l15] = (u8)(signed char)(int)hi;
        pub_[(8 + rr) * 16 + l15] = (u8)(signed char)(int)lo;
      }
    }
    asm volatile("s_waitcnt lgkmcnt(0)" ::: "memory");
    if (lane < 16) {
      uint4 v = *(const uint4*)&pub_[lane * 16];
      u8* dst = himg + (size_t)((t & 1) * 16384) +
                (size_t)(((slot >> 2) * 64 + (slot & 3) * 16 + lane) * 16);
      *(uint4*)dst = v;   // write-through vL1 -> L2
    }
    VMWAIT0();            // h stores acked before tag release
    if (lane == 0) ast32(mytag, (u32)t);
    ((volatile u32*)flg)[2] = (u32)t;
  }

  // ================= FC epilogue (h_512 = himg parity 0) =================
  { u32 tv; do { tv = ald32(tags + lane * 16); } while (!__all(tv >= (u32)SEQ)); }
  CBAR();
  if (tid < 64) {
    const int row = tid >> 3, c8 = tid & 7;     // 8 rows x 8 cols per block
    const int ocol = slot * 8 + c8;
    const float* wr = fcw + (size_t)ocol * 1024;
    float acc = fcb[ocol];
    const float C1 = 1.f / 127.f, C2 = 1.f / 32258.f;
    for (int ks = 0; ks < 16; ++ks) {
#pragma unroll
      for (int kg = 0; kg < 4; ++kg) {
        union { i32x4 v; signed char b[16]; } H, L;
        H.v = ald128(himg + (size_t)((ks * 64 + kg * 16 + row) * 16));
        L.v = ald128(himg + (size_t)((ks * 64 + kg * 16 + 8 + row) * 16));
        const float* wp = wr + ks * 64 + kg * 16;
#pragma unroll
        for (int j = 0; j < 16; ++j)
          acc += ((float)H.b[j] * C1 + (float)L.b[j] * C2) * wp[j];
      }
    }
    out[(size_t)(g * 8 + row) * 512 + ocol] = acc;
  }
}

// ---------- launch ----------
extern "C" void kernel_launch(void* const* d_in, const int* in_sizes, int n_in,
                              void* d_out, int out_size, void* d_ws, size_t ws_size,
                              hipStream_t stream) {
  const float* x  = (const float*)d_in[0];
  const float* W0 = (const float*)d_in[1];
  const float* W1 = (const float*)d_in[2];
  const float* W2 = (const float*)d_in[3];
  const float* W3 = (const float*)d_in[4];
  const float* bi = (const float*)d_in[5];
  const float* bf = (const float*)d_in[6];
  const float* bc = (const float*)d_in[7];
  const float* bo = (const float*)d_in[8];
  const float* fcw = (const float*)d_in[9];
  const float* fcb = (const float*)d_in[10];
  float* out = (float*)d_out;

  char* ws = (char*)d_ws;
  pack_xq<<<dim3(32768), dim3(64), 0, stream>>>(x, (u8*)(ws + OFF_XBQ),
                                                (float*)(ws + OFF_SXG));
  calc_scales<<<dim3(32), dim3(256), 0, stream>>>(W0, W1, W2, W3, (float*)(ws + OFF_SCL));
  pack_whq<<<dim3(1024), dim3(256), 0, stream>>>(W0, W1, W2, W3,
                                                 (const float*)(ws + OFF_SCL),
                                                 (u8*)(ws + OFF_WHQ));
  pack_wxq<<<dim3(512), dim3(256), 0, stream>>>(W0, W1, W2, W3,
                                                (const float*)(ws + OFF_SCL),
                                                (u8*)(ws + OFF_WXQ));
  // zero himg + tags + ctl (contiguous: 262144 + 32768 + 1024)
  hipMemsetAsync(ws + OFF_HIMG, 0, 262144 + 32768 + 1024, stream);
  lstm_main<<<dim3(512), dim3(192), 0, stream>>>(ws, bi, bf, bc, bo, fcw, fcb, out);
}

// Round 16
// 1835.438 us; speedup vs baseline: 2.1993x; 1.4046x over previous
//
#include <hip/hip_runtime.h>

typedef unsigned char u8;
typedef unsigned short u16;
typedef unsigned int u32;
typedef unsigned long long u64;
typedef __attribute__((ext_vector_type(4))) int i32x4;
typedef __attribute__((ext_vector_type(4))) float f32x4;

#define SEQ 512

// ---- ws layout (bytes) ----
#define OFF_XBQ  0ull          // 32 MB : xbq [c 128][g 8][hl 2][mt 2][ks 8][lane 64][16] i8
#define OFF_WXQ  33554432ull   //  2 MB : wxq [slot 32][w 2][q 4][ks 8][lane 64][16] i8
#define OFF_WHQ  35651584ull   //  4 MB : whq [slot 32][w 2][q 4][ks 16][lane 64][16] i8
#define OFF_SCL  39845888ull   // 32 KB : scl [part 2][q 4][1024] f32 (0:x, 1:h; = max|col|/127)
#define OFF_SXG  39878656ull   // 128 KB: sxg [tau 512][brow 64] f32 per-token x scale
#define OFF_HIMG 40009728ull   // 256 KB: himg [g 8][par 2][ks 16][lane 64][16] i8
                               //         (A rows 0-7 = h_hi, rows 8-15 = h_lo)
#define OFF_TAG  40271872ull   // 32 KB : tags [g 8][64] u32, 64B stride (1 writer/line)
#define OFF_CTL  40305152ull   // 512 B : xcnt[8] @ g*64

// ---------- helpers ----------
__device__ inline u16 f2bf(float f) {
  u32 u = __float_as_uint(f);
  return (u16)((u + 0x7fffu + ((u >> 16) & 1u)) >> 16);   // RNE
}
__device__ inline float bf2f(u16 u) { return __uint_as_float(((u32)u) << 16); }
__device__ inline float sigm(float x) { return 1.f / (1.f + __expf(-x)); }
__device__ inline float tanh_(float x) { return 1.f - 2.f / (1.f + __expf(2.f * x)); }

#define MFMA_I8(a, b, c_) __builtin_amdgcn_mfma_i32_16x16x64_i8(a, b, c_, 0, 0, 0)

// agent-scope relaxed atomics — r8-proven; kept for election + poll watchdog.
__device__ inline u32 ald32(const u32* p) {
  return __hip_atomic_load(p, __ATOMIC_RELAXED, __HIP_MEMORY_SCOPE_AGENT);
}
// plain write-through tag store (same-XCD consumers; ordered after VMWAIT0)
__device__ inline void st32_plain(u32* p, u32 v) {
  asm volatile("global_store_dword %0, %1, off" :: "v"(p), "v"(v) : "memory");
}
#define VMWAIT0() asm volatile("s_waitcnt vmcnt(0)" ::: "memory")
#define L1INV()   asm volatile("buffer_inv" ::: "memory")   // vector-L1 invalidate (per-CU)
#define CBAR()    asm volatile("" ::: "memory")

// ---------- prep: x -> per-token-scaled i8 hi/lo A-fragment image ----------
__global__ void pack_xq(const float* __restrict__ x, u8* __restrict__ xbq,
                        float* __restrict__ sxg) {
  __shared__ u8 st[1024];
  const int bid = blockIdx.x;           // brow*512 + tau (32768 blocks, 64 thr)
  const int brow = bid >> 9, tau = bid & 511;
  const int lane = threadIdx.x;
  const float* src = x + ((size_t)bid << 9) + lane * 8;
  float4 a = *(const float4*)src;
  float4 b = *(const float4*)(src + 4);
  float v[8] = {a.x, a.y, a.z, a.w, b.x, b.y, b.z, b.w};
  float m = 0.f;
#pragma unroll
  for (int j = 0; j < 8; ++j) m = fmaxf(m, fabsf(v[j]));
#pragma unroll
  for (int i = 1; i < 64; i <<= 1) m = fmaxf(m, __shfl_xor(m, i));
  m = fmaxf(m, 1e-20f);
  const float s = m * (1.f / 127.f), inv = 127.f / m;
#pragma unroll
  for (int j = 0; j < 8; ++j) {
    float t = v[j] * inv;                 // |t| <= 127
    float hi = rintf(t);
    float lo = rintf((t - hi) * 254.f);
    st[lane * 8 + j] = (u8)(signed char)(int)hi;
    st[512 + lane * 8 + j] = (u8)(signed char)(int)lo;
  }
  __syncthreads();
  const int hl = lane >> 5, ks = (lane >> 2) & 7, kg = lane & 3;
  uint4 u = *(const uint4*)&st[hl * 512 + ks * 64 + kg * 16];
  const int c = tau >> 2, tc = tau & 3, g = brow >> 3, rb = brow & 7;
  const int mrow = tc * 8 + rb, mt = mrow >> 4, m15 = mrow & 15;
  *(uint4*)(xbq + (size_t)(((((c * 8 + g) * 2 + hl) * 2 + mt) * 8 + ks) * 64 +
                           kg * 16 + m15) * 16) = u;
  if (lane == 0) sxg[tau * 64 + brow] = s;
}

// ---------- prep: per-gate-column scales ----------
__global__ void calc_scales(const float* __restrict__ W0, const float* __restrict__ W1,
                            const float* __restrict__ W2, const float* __restrict__ W3,
                            float* __restrict__ scl) {
  const int id = blockIdx.x * 256 + threadIdx.x;   // 8192
  const int part = id >> 12, q = (id >> 10) & 3, cc = id & 1023;
  const float* Wg = q == 0 ? W0 : q == 1 ? W1 : q == 2 ? W2 : W3;
  const int r0 = part ? 512 : 0, n = part ? 1024 : 512;
  float mx = 1e-8f;
  for (int k = 0; k < n; ++k) mx = fmaxf(mx, fabsf(Wg[(size_t)(r0 + k) * 1024 + cc]));
  scl[id] = mx * (1.f / 127.f);
}

// ---------- prep: W_h -> i8 B-fragment image (K=1024) ----------
__global__ void pack_whq(const float* __restrict__ W0, const float* __restrict__ W1,
                         const float* __restrict__ W2, const float* __restrict__ W3,
                         const float* __restrict__ scl, u8* __restrict__ whq) {
  const int id = blockIdx.x * 256 + threadIdx.x;    // 262,144 units
  const int lane = id & 63, ks = (id >> 6) & 15, q = (id >> 10) & 3;
  const int w = (id >> 12) & 1, slot = id >> 13;
  const int hcol = slot * 32 + w * 16 + (lane & 15);
  const float* Wg = q == 0 ? W0 : q == 1 ? W1 : q == 2 ? W2 : W3;
  const int k0 = ks * 64 + (lane >> 4) * 16;
  const float inv_s = 1.f / scl[4096 + q * 1024 + hcol];
  u8 tmp[16];
#pragma unroll
  for (int j = 0; j < 16; ++j) {
    float v = Wg[(size_t)(512 + k0 + j) * 1024 + hcol] * inv_s;
    tmp[j] = (u8)(signed char)(int)rintf(fminf(fmaxf(v, -127.f), 127.f));
  }
  *(uint4*)(whq + (size_t)id * 16) = *(uint4*)tmp;
}

// ---------- prep: W_x -> i8 B-fragment image (K=512) ----------
__global__ void pack_wxq(const float* __restrict__ W0, const float* __restrict__ W1,
                         const float* __restrict__ W2, const float* __restrict__ W3,
                         const float* __restrict__ scl, u8* __restrict__ wxq) {
  const int id = blockIdx.x * 256 + threadIdx.x;    // 131,072 units
  const int lane = id & 63, ks = (id >> 6) & 7, q = (id >> 9) & 3;
  const int w = (id >> 11) & 1, slot = id >> 12;
  const int hcol = slot * 32 + w * 16 + (lane & 15);
  const float* Wg = q == 0 ? W0 : q == 1 ? W1 : q == 2 ? W2 : W3;
  const int k0 = ks * 64 + (lane >> 4) * 16;
  const float inv_s = 1.f / scl[q * 1024 + hcol];
  u8 tmp[16];
#pragma unroll
  for (int j = 0; j < 16; ++j) {
    float v = Wg[(size_t)(k0 + j) * 1024 + hcol] * inv_s;
    tmp[j] = (u8)(signed char)(int)rintf(fminf(fmaxf(v, -127.f), 127.f));
  }
  *(uint4*)(wxq + (size_t)id * 16) = *(uint4*)tmp;
}

// ---------- main persistent kernel ----------
// 256 blocks x 192 thr (3 waves). group g = XCD id; slot via L2 atomic; 1 block/CU
// by LDS pigeonhole. r12 structure; hot read path = volatile/plain loads with
// per-quarter buffer_inv (vL1 invalidate) instead of atomic loads; tag release =
// plain write-through store after vmcnt(0). Watchdog: poll falls back to agent
// loads after 2^20 spins (no-deadlock guarantee). Producer: gates_x -> LDS ring.
__global__ void __launch_bounds__(192, 1) lstm_main(
    char* __restrict__ ws,
    const float* __restrict__ b_i, const float* __restrict__ b_f,
    const float* __restrict__ b_c, const float* __restrict__ b_o,
    const float* __restrict__ fcw, const float* __restrict__ fcb,
    float* __restrict__ out) {
  __shared__ __align__(16) u8 wh[131072];      // [w 2][q 4][ks 16][lane 64][16] i8
  __shared__ __align__(16) u16 ring_[8192];    // 16KB [par 2][tc 4][cc 128][rb 8] bf16
  __shared__ __align__(16) u8 pub_[512];       // [w 2][row 16][col 16] i8
  __shared__ u32 flg[16];                      // 0:slot 1:pc 2,3:ct[w]

  const int tid = threadIdx.x;
  const int wid = tid >> 6;
  const int lane = tid & 63;
  const int kgrp = lane >> 4;
  const int l15 = lane & 15;

  u32 xcd;
  asm volatile("s_getreg_b32 %0, hwreg(HW_REG_XCC_ID, 0, 8)" : "=s"(xcd));
  const int g = (int)(xcd & 7);

  if (tid == 0) {
    u32 s = __hip_atomic_fetch_add((u32*)(ws + OFF_CTL) + g * 16, 1u,
                                   __ATOMIC_RELAXED, __HIP_MEMORY_SCOPE_SYSTEM);
    flg[0] = s; flg[1] = 0; flg[2] = 0; flg[3] = 0;
  }
  __syncthreads();
  const int slot = (int)flg[0];
  if (slot >= 32) return;   // cannot happen (1 block/CU pigeonhole)

  u8* himg = (u8*)(ws + OFF_HIMG) + (size_t)g * 32768;
  u32* tags = (u32*)(ws + OFF_TAG) + g * 1024;   // 64 tags @ 64B stride
  const float* scl = (const float*)(ws + OFF_SCL);

  // one-time W_h LDS fill (8192 x 16B units, 192 threads)
  {
    const u8* src = (const u8*)(ws + OFF_WHQ) + (size_t)slot * 131072;
    for (int i = 0; i < 43; ++i) {
      int u = i * 192 + tid;
      if (u < 8192) *(uint4*)&wh[u * 16] = *(const uint4*)(src + u * 16);
    }
  }
  __syncthreads();

  if (wid == 2) {
    // ================= producer wave: gates_x -> LDS ring =================
    const u8* xq = (const u8*)(ws + OFF_XBQ);
    const u8* wxs = (const u8*)(ws + OFF_WXQ) + (size_t)slot * 65536;
    const float* sxg = (const float*)(ws + OFF_SXG);
    float swx[2][4], bs[2][4];
#pragma unroll
    for (int w2 = 0; w2 < 2; ++w2) {
      const int cwq = slot * 32 + w2 * 16 + l15;
#pragma unroll
      for (int q = 0; q < 4; ++q) swx[w2][q] = scl[q * 1024 + cwq];
      bs[w2][0] = b_i[cwq]; bs[w2][1] = b_f[cwq];
      bs[w2][2] = b_c[cwq]; bs[w2][3] = b_o[cwq];
    }
    for (int c = 0; c < 128; ++c) {
      if (c >= 2) {
        const u32 need = (u32)(4 * c - 4);
        while (((volatile u32*)flg)[2] < need || ((volatile u32*)flg)[3] < need) {}
        CBAR();
      }
      float sxv[2][4];
#pragma unroll
      for (int mt = 0; mt < 2; ++mt)
#pragma unroll
        for (int r = 0; r < 4; ++r)
          sxv[mt][r] = sxg[(c * 4 + mt * 2 + (kgrp >> 1)) * 64 + g * 8 + (kgrp & 1) * 4 + r];
      i32x4 accH[2][2][4], accL[2][2][4];
#pragma unroll
      for (int mt = 0; mt < 2; ++mt)
#pragma unroll
        for (int w2 = 0; w2 < 2; ++w2)
#pragma unroll
          for (int q = 0; q < 4; ++q) {
            accH[mt][w2][q] = (i32x4){0, 0, 0, 0};
            accL[mt][w2][q] = (i32x4){0, 0, 0, 0};
          }
      const u8* xc = xq + (size_t)(c * 8 + g) * 32768;
#pragma unroll 2
      for (int ks = 0; ks < 8; ++ks) {
        i32x4 aH0 = *(const i32x4*)(xc + (size_t)((0 * 2 + 0) * 8 + ks) * 1024 + lane * 16);
        i32x4 aH1 = *(const i32x4*)(xc + (size_t)((0 * 2 + 1) * 8 + ks) * 1024 + lane * 16);
        i32x4 aL0 = *(const i32x4*)(xc + (size_t)((1 * 2 + 0) * 8 + ks) * 1024 + lane * 16);
        i32x4 aL1 = *(const i32x4*)(xc + (size_t)((1 * 2 + 1) * 8 + ks) * 1024 + lane * 16);
#pragma unroll
        for (int w2 = 0; w2 < 2; ++w2)
#pragma unroll
          for (int q = 0; q < 4; ++q) {
            i32x4 b = *(const i32x4*)(wxs + (size_t)(((w2 * 4 + q) * 8 + ks) * 64 + lane) * 16);
            accH[0][w2][q] = MFMA_I8(aH0, b, accH[0][w2][q]);
            accH[1][w2][q] = MFMA_I8(aH1, b, accH[1][w2][q]);
            accL[0][w2][q] = MFMA_I8(aL0, b, accL[0][w2][q]);
            accL[1][w2][q] = MFMA_I8(aL1, b, accL[1][w2][q]);
          }
      }
#pragma unroll
      for (int mt = 0; mt < 2; ++mt)
#pragma unroll
        for (int w2 = 0; w2 < 2; ++w2)
#pragma unroll
          for (int q = 0; q < 4; ++q) {
            u64 pk = 0;
#pragma unroll
            for (int r = 0; r < 4; ++r) {
              float val = sxv[mt][r] * swx[w2][q] *
                          ((float)accH[mt][w2][q][r] + (float)accL[mt][w2][q][r] * (1.f / 254.f)) +
                          bs[w2][q];
              pk |= (u64)f2bf(val) << (16 * r);
            }
            const int tc = mt * 2 + (kgrp >> 1);
            const int cc2 = (w2 * 4 + q) * 16 + l15;
            const int rb0 = (kgrp & 1) * 4;
            *(u64*)&ring_[(((c & 1) * 4 + tc) * 128 + cc2) * 8 + rb0] = pk;
          }
      asm volatile("s_waitcnt lgkmcnt(0)" ::: "memory");
      ((volatile u32*)flg)[1] = (u32)(c + 1);
    }
    return;
  }

  // ================= consumer waves (w = wid in {0,1}) =================
  const int w = wid;
  const int col = slot * 32 + w * 16 + l15;
  const int idx = slot * 2 + w;              // publish tile id
  float sA[4];
#pragma unroll
  for (int q = 0; q < 4; ++q) sA[q] = scl[4096 + q * 1024 + col] * (1.f / 127.f);

  float cs[4] = {0.f, 0.f, 0.f, 0.f};
  u32* mytag = tags + idx * 16;
  const volatile u32* mypoll = (const volatile u32*)(tags + lane * 16);
  const int rbb = (kgrp & 1) * 4;

  for (int t = 1; t <= SEQ; ++t) {
    const int tau = t - 1, ch = tau >> 2, tc = tau & 3, par = tau & 1;
    // gates_x from LDS ring
    while (((volatile u32*)flg)[1] <= (u32)ch) {}
    CBAR();
    f32x4 gx[4];
#pragma unroll
    for (int q = 0; q < 4; ++q) {
      u64 pk = *(const u64*)&ring_[(((ch & 1) * 4 + tc) * 128 + (w * 4 + q) * 16 + l15) * 8 + rbb];
      gx[q][0] = bf2f((u16)pk);         gx[q][1] = bf2f((u16)(pk >> 16));
      gx[q][2] = bf2f((u16)(pk >> 32)); gx[q][3] = bf2f((u16)(pk >> 48));
    }
    // ---- quarter-gated consumption: volatile poll -> L1 inv -> plain loads ----
    const u8* ab = himg + par * 16384 + lane * 16;
    u32 spins = 0;
    u64 rb = __ballot(*mypoll >= (u32)tau);
    i32x4 A[16];
    i32x4 acc[4];
#pragma unroll
    for (int q = 0; q < 4; ++q) acc[q] = (i32x4){0, 0, 0, 0};
#pragma unroll
    for (int q4 = 0; q4 < 4; ++q4) {
      const u64 need = 0xFFFFull << (q4 * 16);
      while ((rb & need) != need) {
        u32 v = (++spins > (1u << 20)) ? ald32((const u32*)mypoll) : *mypoll;
        rb = __ballot(v >= (u32)tau);
      }
      CBAR();
      L1INV();          // drop stale L1 lines; fresh copies live in same-XCD L2
#pragma unroll
      for (int k4 = 0; k4 < 4; ++k4)
        A[q4 * 4 + k4] = *(const i32x4*)(ab + (size_t)(q4 * 4 + k4) * 1024);
      if (q4 > 0) {
#pragma unroll
        for (int k4 = 0; k4 < 4; ++k4) {
          const int ks = (q4 - 1) * 4 + k4;
#pragma unroll
          for (int q = 0; q < 4; ++q) {
            i32x4 b = *(const i32x4*)&wh[(size_t)(((w * 4 + q) * 16 + ks) * 64 + lane) * 16];
            acc[q] = MFMA_I8(A[ks], b, acc[q]);
          }
        }
      }
    }
#pragma unroll
    for (int k4 = 0; k4 < 4; ++k4) {
      const int ks = 12 + k4;
#pragma unroll
      for (int q = 0; q < 4; ++q) {
        i32x4 b = *(const i32x4*)&wh[(size_t)(((w * 4 + q) * 16 + ks) * 64 + lane) * 16];
        acc[q] = MFMA_I8(A[ks], b, acc[q]);
      }
    }
    // recombine hi/lo, gates, cell state, quantize h, stage
#pragma unroll
    for (int r = 0; r < 4; ++r) {
      float p[4];
#pragma unroll
      for (int q = 0; q < 4; ++q) {
        float hiF = (float)acc[q][r];
        float loF = (float)__shfl_xor(acc[q][r], 32);
        p[q] = fmaf(sA[q], fmaf(loF, 1.f / 254.f, hiF), gx[q][r]);
      }
      float iv = sigm(p[0]), fv = sigm(p[1]), gv = tanh_(p[2]), ov = sigm(p[3]);
      float cn = fv * cs[r] + iv * gv;
      cs[r] = cn;
      float h = ov * tanh_(cn);
      float hq = h * 127.f;
      float hi = rintf(hq);
      float lo = rintf((hq - hi) * 254.f);
      if (kgrp < 2) {
        const int rr = kgrp * 4 + r;
        pub_[w * 256 + rr * 16 + l15] = (u8)(signed char)(int)hi;
        pub_[w * 256 + (8 + rr) * 16 + l15] = (u8)(signed char)(int)lo;
      }
    }
    asm volatile("s_waitcnt lgkmcnt(0)" ::: "memory");
    if (lane < 16) {
      uint4 v = *(const uint4*)&pub_[w * 256 + lane * 16];
      u8* dst = himg + (size_t)((t & 1) * 16384) +
                (size_t)(((idx >> 2) * 64 + (idx & 3) * 16 + lane) * 16);
      *(uint4*)dst = v;   // write-through vL1 -> own-XCD L2
    }
    VMWAIT0();            // h stores acked at L2 before tag release
    if (lane == 0) st32_plain(mytag, (u32)t);
    ((volatile u32*)flg)[2 + w] = (u32)t;
  }

  // ================= FC epilogue (h_512 = himg parity 0) =================
  {
    u32 spins = 0;
    u64 rb = __ballot(*mypoll >= (u32)SEQ);
    while (rb != ~0ull) {
      u32 v = (++spins > (1u << 20)) ? ald32((const u32*)mypoll) : *mypoll;
      rb = __ballot(v >= (u32)SEQ);
    }
  }
  CBAR();
  L1INV();
  {
    const int row = tid >> 4, c16 = tid & 15;   // tid 0-127: rows 0-7
    const int ocol = slot * 16 + c16;
    const float* wr = fcw + (size_t)ocol * 1024;
    float acc = fcb[ocol];
    const float C1 = 1.f / 127.f, C2 = 1.f / 32258.f;
    for (int ks = 0; ks < 16; ++ks) {
#pragma unroll
      for (int kg = 0; kg < 4; ++kg) {
        union { i32x4 v; signed char b[16]; } H, L;
        H.v = *(const i32x4*)(himg + (size_t)((ks * 64 + kg * 16 + row) * 16));
        L.v = *(const i32x4*)(himg + (size_t)((ks * 64 + kg * 16 + 8 + row) * 16));
        const float* wp = wr + ks * 64 + kg * 16;
#pragma unroll
        for (int j = 0; j < 16; ++j)
          acc += ((float)H.b[j] * C1 + (float)L.b[j] * C2) * wp[j];
      }
    }
    out[(size_t)(g * 8 + row) * 512 + ocol] = acc;
  }
}

// ---------- launch ----------
extern "C" void kernel_launch(void* const* d_in, const int* in_sizes, int n_in,
                              void* d_out, int out_size, void* d_ws, size_t ws_size,
                              hipStream_t stream) {
  const float* x  = (const float*)d_in[0];
  const float* W0 = (const float*)d_in[1];
  const float* W1 = (const float*)d_in[2];
  const float* W2 = (const float*)d_in[3];
  const float* W3 = (const float*)d_in[4];
  const float* bi = (const float*)d_in[5];
  const float* bf = (const float*)d_in[6];
  const float* bc = (const float*)d_in[7];
  const float* bo = (const float*)d_in[8];
  const float* fcw = (const float*)d_in[9];
  const float* fcb = (const float*)d_in[10];
  float* out = (float*)d_out;

  char* ws = (char*)d_ws;
  pack_xq<<<dim3(32768), dim3(64), 0, stream>>>(x, (u8*)(ws + OFF_XBQ),
                                                (float*)(ws + OFF_SXG));
  calc_scales<<<dim3(32), dim3(256), 0, stream>>>(W0, W1, W2, W3, (float*)(ws + OFF_SCL));
  pack_whq<<<dim3(1024), dim3(256), 0, stream>>>(W0, W1, W2, W3,
                                                 (const float*)(ws + OFF_SCL),
                                                 (u8*)(ws + OFF_WHQ));
  pack_wxq<<<dim3(512), dim3(256), 0, stream>>>(W0, W1, W2, W3,
                                                (const float*)(ws + OFF_SCL),
                                                (u8*)(ws + OFF_WXQ));
  // zero himg + tags + ctl (contiguous span through OFF_CTL+512)
  hipMemsetAsync(ws + OFF_HIMG, 0, 262144 + 32768 + 1024, stream);
  lstm_main<<<dim3(256), dim3(192), 0, stream>>>(ws, bi, bf, bc, bo, fcw, fcb, out);
}

// Round 17
// 1661.063 us; speedup vs baseline: 2.4302x; 1.1050x over previous
//
#include <hip/hip_runtime.h>

typedef unsigned char u8;
typedef unsigned short u16;
typedef unsigned int u32;
typedef unsigned long long u64;
typedef __attribute__((ext_vector_type(4))) int i32x4;
typedef __attribute__((ext_vector_type(4))) float f32x4;

#define SEQ 512
#define L2E  1.4426950408889634f
#define L2E2 2.8853900817779268f

// ---- ws layout (bytes) ----
#define OFF_XBQ  0ull          // 32 MB : xbq [c 128][g 8][hl 2][mt 2][ks 8][lane 64][16] i8
#define OFF_WXQ  33554432ull   //  2 MB : wxq [slot 32][w 2][q 4][ks 8][lane 64][16] i8
#define OFF_WHQ  35651584ull   //  4 MB : whq [slot 32][w 2][q 4][ks 16][lane 64][16] i8
#define OFF_SCL  39845888ull   // 32 KB : scl [part 2][q 4][1024] f32 (0:x, 1:h; = max|col|/127)
#define OFF_SXG  39878656ull   // 128 KB: sxg [tau 512][brow 64] f32 per-token x scale
#define OFF_HIMG 40009728ull   // 256 KB: himg [g 8][par 2][ks 16][lane 64][16] i8
                               //         (A rows 0-7 = h_hi, rows 8-15 = h_lo)
#define OFF_TAG  40271872ull   // 32 KB : tags [g 8][64] u32, 64B stride (1 writer/line)
#define OFF_CTL  40305152ull   // 512 B : xcnt[8] @ g*64

// ---------- helpers ----------
__device__ inline u16 f2bf(float f) {
  u32 u = __float_as_uint(f);
  return (u16)((u + 0x7fffu + ((u >> 16) & 1u)) >> 16);   // RNE
}
__device__ inline float bf2f(u16 u) { return __uint_as_float(((u32)u) << 16); }

#if __has_builtin(__builtin_amdgcn_exp2f)
#define EXP2(x) __builtin_amdgcn_exp2f(x)
#else
#define EXP2(x) exp2f(x)
#endif
#if __has_builtin(__builtin_amdgcn_rcpf)
#define RCP(x) __builtin_amdgcn_rcpf(x)
#else
#define RCP(x) (1.f / (x))
#endif
// p already scaled by log2e:
__device__ inline float sigm2(float p) { return RCP(1.f + EXP2(-p)); }
// p already scaled by 2*log2e:
__device__ inline float tanh2(float p) { return 1.f - 2.f * RCP(1.f + EXP2(p)); }

#define MFMA_I8(a, b, c_) __builtin_amdgcn_mfma_i32_16x16x64_i8(a, b, c_, 0, 0, 0)

// agent-scope relaxed atomics — r8-proven; kept for election + poll watchdog.
__device__ inline u32 ald32(const u32* p) {
  return __hip_atomic_load(p, __ATOMIC_RELAXED, __HIP_MEMORY_SCOPE_AGENT);
}
// plain write-through tag store (same-XCD consumers; ordered after VMWAIT0)
__device__ inline void st32_plain(u32* p, u32 v) {
  asm volatile("global_store_dword %0, %1, off" :: "v"(p), "v"(v) : "memory");
}
#define VMWAIT0() asm volatile("s_waitcnt vmcnt(0)" ::: "memory")
#define L1INV()   asm volatile("buffer_inv" ::: "memory")   // vector-L1 invalidate (per-CU)
#define CBAR()    asm volatile("" ::: "memory")

// ---------- prep: x -> per-token-scaled i8 hi/lo A-fragment image ----------
__global__ void pack_xq(const float* __restrict__ x, u8* __restrict__ xbq,
                        float* __restrict__ sxg) {
  __shared__ u8 st[1024];
  const int bid = blockIdx.x;           // brow*512 + tau (32768 blocks, 64 thr)
  const int brow = bid >> 9, tau = bid & 511;
  const int lane = threadIdx.x;
  const float* src = x + ((size_t)bid << 9) + lane * 8;
  float4 a = *(const float4*)src;
  float4 b = *(const float4*)(src + 4);
  float v[8] = {a.x, a.y, a.z, a.w, b.x, b.y, b.z, b.w};
  float m = 0.f;
#pragma unroll
  for (int j = 0; j < 8; ++j) m = fmaxf(m, fabsf(v[j]));
#pragma unroll
  for (int i = 1; i < 64; i <<= 1) m = fmaxf(m, __shfl_xor(m, i));
  m = fmaxf(m, 1e-20f);
  const float s = m * (1.f / 127.f), inv = 127.f / m;
#pragma unroll
  for (int j = 0; j < 8; ++j) {
    float t = v[j] * inv;                 // |t| <= 127
    float hi = rintf(t);
    float lo = rintf((t - hi) * 254.f);
    st[lane * 8 + j] = (u8)(signed char)(int)hi;
    st[512 + lane * 8 + j] = (u8)(signed char)(int)lo;
  }
  __syncthreads();
  const int hl = lane >> 5, ks = (lane >> 2) & 7, kg = lane & 3;
  uint4 u = *(const uint4*)&st[hl * 512 + ks * 64 + kg * 16];
  const int c = tau >> 2, tc = tau & 3, g = brow >> 3, rb = brow & 7;
  const int mrow = tc * 8 + rb, mt = mrow >> 4, m15 = mrow & 15;
  *(uint4*)(xbq + (size_t)(((((c * 8 + g) * 2 + hl) * 2 + mt) * 8 + ks) * 64 +
                           kg * 16 + m15) * 16) = u;
  if (lane == 0) sxg[tau * 64 + brow] = s;
}

// ---------- prep: per-gate-column scales ----------
__global__ void calc_scales(const float* __restrict__ W0, const float* __restrict__ W1,
                            const float* __restrict__ W2, const float* __restrict__ W3,
                            float* __restrict__ scl) {
  const int id = blockIdx.x * 256 + threadIdx.x;   // 8192
  const int part = id >> 12, q = (id >> 10) & 3, cc = id & 1023;
  const float* Wg = q == 0 ? W0 : q == 1 ? W1 : q == 2 ? W2 : W3;
  const int r0 = part ? 512 : 0, n = part ? 1024 : 512;
  float mx = 1e-8f;
  for (int k = 0; k < n; ++k) mx = fmaxf(mx, fabsf(Wg[(size_t)(r0 + k) * 1024 + cc]));
  scl[id] = mx * (1.f / 127.f);
}

// ---------- prep: W_h -> i8 B-fragment image (K=1024) ----------
__global__ void pack_whq(const float* __restrict__ W0, const float* __restrict__ W1,
                         const float* __restrict__ W2, const float* __restrict__ W3,
                         const float* __restrict__ scl, u8* __restrict__ whq) {
  const int id = blockIdx.x * 256 + threadIdx.x;    // 262,144 units
  const int lane = id & 63, ks = (id >> 6) & 15, q = (id >> 10) & 3;
  const int w = (id >> 12) & 1, slot = id >> 13;
  const int hcol = slot * 32 + w * 16 + (lane & 15);
  const float* Wg = q == 0 ? W0 : q == 1 ? W1 : q == 2 ? W2 : W3;
  const int k0 = ks * 64 + (lane >> 4) * 16;
  const float inv_s = 1.f / scl[4096 + q * 1024 + hcol];
  u8 tmp[16];
#pragma unroll
  for (int j = 0; j < 16; ++j) {
    float v = Wg[(size_t)(512 + k0 + j) * 1024 + hcol] * inv_s;
    tmp[j] = (u8)(signed char)(int)rintf(fminf(fmaxf(v, -127.f), 127.f));
  }
  *(uint4*)(whq + (size_t)id * 16) = *(uint4*)tmp;
}

// ---------- prep: W_x -> i8 B-fragment image (K=512) ----------
__global__ void pack_wxq(const float* __restrict__ W0, const float* __restrict__ W1,
                         const float* __restrict__ W2, const float* __restrict__ W3,
                         const float* __restrict__ scl, u8* __restrict__ wxq) {
  const int id = blockIdx.x * 256 + threadIdx.x;    // 131,072 units
  const int lane = id & 63, ks = (id >> 6) & 7, q = (id >> 9) & 3;
  const int w = (id >> 11) & 1, slot = id >> 12;
  const int hcol = slot * 32 + w * 16 + (lane & 15);
  const float* Wg = q == 0 ? W0 : q == 1 ? W1 : q == 2 ? W2 : W3;
  const int k0 = ks * 64 + (lane >> 4) * 16;
  const float inv_s = 1.f / scl[q * 1024 + hcol];
  u8 tmp[16];
#pragma unroll
  for (int j = 0; j < 16; ++j) {
    float v = Wg[(size_t)(k0 + j) * 1024 + hcol] * inv_s;
    tmp[j] = (u8)(signed char)(int)rintf(fminf(fmaxf(v, -127.f), 127.f));
  }
  *(uint4*)(wxq + (size_t)id * 16) = *(uint4*)tmp;
}

// ---------- main persistent kernel ----------
// r16 skeleton + (a) bulk fast-path A-load when all 64 tags ready (single latency
// exposure), (b) exp2-folded gates (log2e folded into scales/biases; rcp+exp2 only),
// (c) direct byte publish (no LDS staging), (d) poll-before-ring, producer s_sleep.
__global__ void __launch_bounds__(192, 1) lstm_main(
    char* __restrict__ ws,
    const float* __restrict__ b_i, const float* __restrict__ b_f,
    const float* __restrict__ b_c, const float* __restrict__ b_o,
    const float* __restrict__ fcw, const float* __restrict__ fcb,
    float* __restrict__ out) {
  __shared__ __align__(16) u8 wh[131072];      // [w 2][q 4][ks 16][lane 64][16] i8
  __shared__ __align__(16) u16 ring_[8192];    // 16KB [par 2][tc 4][cc 128][rb 8] bf16
  __shared__ u32 flg[16];                      // 0:slot 1:pc 2,3:ct[w]

  const int tid = threadIdx.x;
  const int wid = tid >> 6;
  const int lane = tid & 63;
  const int kgrp = lane >> 4;
  const int l15 = lane & 15;

  u32 xcd;
  asm volatile("s_getreg_b32 %0, hwreg(HW_REG_XCC_ID, 0, 8)" : "=s"(xcd));
  const int g = (int)(xcd & 7);

  if (tid == 0) {
    u32 s = __hip_atomic_fetch_add((u32*)(ws + OFF_CTL) + g * 16, 1u,
                                   __ATOMIC_RELAXED, __HIP_MEMORY_SCOPE_SYSTEM);
    flg[0] = s; flg[1] = 0; flg[2] = 0; flg[3] = 0;
  }
  __syncthreads();
  const int slot = (int)flg[0];
  if (slot >= 32) return;   // cannot happen (1 block/CU pigeonhole)

  u8* himg = (u8*)(ws + OFF_HIMG) + (size_t)g * 32768;
  u32* tags = (u32*)(ws + OFF_TAG) + g * 1024;   // 64 tags @ 64B stride
  const float* scl = (const float*)(ws + OFF_SCL);

  // one-time W_h LDS fill (8192 x 16B units, 192 threads)
  {
    const u8* src = (const u8*)(ws + OFF_WHQ) + (size_t)slot * 131072;
    for (int i = 0; i < 43; ++i) {
      int u = i * 192 + tid;
      if (u < 8192) *(uint4*)&wh[u * 16] = *(const uint4*)(src + u * 16);
    }
  }
  __syncthreads();

  if (wid == 2) {
    // ================= producer wave: gates_x -> LDS ring =================
    const u8* xq = (const u8*)(ws + OFF_XBQ);
    const u8* wxs = (const u8*)(ws + OFF_WXQ) + (size_t)slot * 65536;
    const float* sxg = (const float*)(ws + OFF_SXG);
    float swx[2][4], bs[2][4];
#pragma unroll
    for (int w2 = 0; w2 < 2; ++w2) {
      const int cwq = slot * 32 + w2 * 16 + l15;
#pragma unroll
      for (int q = 0; q < 4; ++q) {
        const float sc = (q == 2) ? L2E2 : L2E;   // fold log2e (2x for tanh gate)
        swx[w2][q] = scl[q * 1024 + cwq] * sc;
      }
      bs[w2][0] = b_i[cwq] * L2E;  bs[w2][1] = b_f[cwq] * L2E;
      bs[w2][2] = b_c[cwq] * L2E2; bs[w2][3] = b_o[cwq] * L2E;
    }
    for (int c = 0; c < 128; ++c) {
      if (c >= 2) {
        const u32 need = (u32)(4 * c - 4);
        while (((volatile u32*)flg)[2] < need || ((volatile u32*)flg)[3] < need)
          __builtin_amdgcn_s_sleep(1);
        CBAR();
      }
      float sxv[2][4];
#pragma unroll
      for (int mt = 0; mt < 2; ++mt)
#pragma unroll
        for (int r = 0; r < 4; ++r)
          sxv[mt][r] = sxg[(c * 4 + mt * 2 + (kgrp >> 1)) * 64 + g * 8 + (kgrp & 1) * 4 + r];
      i32x4 accH[2][2][4], accL[2][2][4];
#pragma unroll
      for (int mt = 0; mt < 2; ++mt)
#pragma unroll
        for (int w2 = 0; w2 < 2; ++w2)
#pragma unroll
          for (int q = 0; q < 4; ++q) {
            accH[mt][w2][q] = (i32x4){0, 0, 0, 0};
            accL[mt][w2][q] = (i32x4){0, 0, 0, 0};
          }
      const u8* xc = xq + (size_t)(c * 8 + g) * 32768;
#pragma unroll 2
      for (int ks = 0; ks < 8; ++ks) {
        i32x4 aH0 = *(const i32x4*)(xc + (size_t)((0 * 2 + 0) * 8 + ks) * 1024 + lane * 16);
        i32x4 aH1 = *(const i32x4*)(xc + (size_t)((0 * 2 + 1) * 8 + ks) * 1024 + lane * 16);
        i32x4 aL0 = *(const i32x4*)(xc + (size_t)((1 * 2 + 0) * 8 + ks) * 1024 + lane * 16);
        i32x4 aL1 = *(const i32x4*)(xc + (size_t)((1 * 2 + 1) * 8 + ks) * 1024 + lane * 16);
#pragma unroll
        for (int w2 = 0; w2 < 2; ++w2)
#pragma unroll
          for (int q = 0; q < 4; ++q) {
            i32x4 b = *(const i32x4*)(wxs + (size_t)(((w2 * 4 + q) * 8 + ks) * 64 + lane) * 16);
            accH[0][w2][q] = MFMA_I8(aH0, b, accH[0][w2][q]);
            accH[1][w2][q] = MFMA_I8(aH1, b, accH[1][w2][q]);
            accL[0][w2][q] = MFMA_I8(aL0, b, accL[0][w2][q]);
            accL[1][w2][q] = MFMA_I8(aL1, b, accL[1][w2][q]);
          }
      }
#pragma unroll
      for (int mt = 0; mt < 2; ++mt)
#pragma unroll
        for (int w2 = 0; w2 < 2; ++w2)
#pragma unroll
          for (int q = 0; q < 4; ++q) {
            u64 pk = 0;
#pragma unroll
            for (int r = 0; r < 4; ++r) {
              float val = sxv[mt][r] * swx[w2][q] *
                          ((float)accH[mt][w2][q][r] + (float)accL[mt][w2][q][r] * (1.f / 254.f)) +
                          bs[w2][q];
              pk |= (u64)f2bf(val) << (16 * r);
            }
            const int tc = mt * 2 + (kgrp >> 1);
            const int cc2 = (w2 * 4 + q) * 16 + l15;
            const int rb0 = (kgrp & 1) * 4;
            *(u64*)&ring_[(((c & 1) * 4 + tc) * 128 + cc2) * 8 + rb0] = pk;
          }
      asm volatile("s_waitcnt lgkmcnt(0)" ::: "memory");
      ((volatile u32*)flg)[1] = (u32)(c + 1);
    }
    return;
  }

  // ================= consumer waves (w = wid in {0,1}) =================
  const int w = wid;
  const int col = slot * 32 + w * 16 + l15;
  const int idx = slot * 2 + w;              // publish tile id
  float sA[4];
#pragma unroll
  for (int q = 0; q < 4; ++q)
    sA[q] = scl[4096 + q * 1024 + col] * (1.f / 127.f) * ((q == 2) ? L2E2 : L2E);

  float cs[4] = {0.f, 0.f, 0.f, 0.f};
  u32* mytag = tags + idx * 16;
  const volatile u32* mypoll = (const volatile u32*)(tags + lane * 16);
  const int rbb = (kgrp & 1) * 4;
  u8* const pubbase = himg + (size_t)(((idx >> 2) * 64 + (idx & 3) * 16) * 16);

  for (int t = 1; t <= SEQ; ++t) {
    const int tau = t - 1, ch = tau >> 2, tc = tau & 3, par = tau & 1;
    // early poll snapshot (before ring read)
    u64 rb = __ballot(*mypoll >= (u32)tau);
    // gates_x from LDS ring
    while (((volatile u32*)flg)[1] <= (u32)ch) {}
    CBAR();
    f32x4 gx[4];
#pragma unroll
    for (int q = 0; q < 4; ++q) {
      u64 pk = *(const u64*)&ring_[(((ch & 1) * 4 + tc) * 128 + (w * 4 + q) * 16 + l15) * 8 + rbb];
      gx[q][0] = bf2f((u16)pk);         gx[q][1] = bf2f((u16)(pk >> 16));
      gx[q][2] = bf2f((u16)(pk >> 32)); gx[q][3] = bf2f((u16)(pk >> 48));
    }
    const u8* ab = himg + par * 16384 + lane * 16;
    i32x4 A[16];
    i32x4 acc[4];
#pragma unroll
    for (int q = 0; q < 4; ++q) acc[q] = (i32x4){0, 0, 0, 0};
    if (rb == ~0ull) {
      // ---- bulk fast path: all tiles ready; one load-latency exposure ----
      CBAR();
      L1INV();
#pragma unroll
      for (int ks = 0; ks < 16; ++ks)
        A[ks] = *(const i32x4*)(ab + (size_t)ks * 1024);
#pragma unroll
      for (int ks = 0; ks < 16; ++ks)
#pragma unroll
        for (int q = 0; q < 4; ++q) {
          i32x4 b = *(const i32x4*)&wh[(size_t)(((w * 4 + q) * 16 + ks) * 64 + lane) * 16];
          acc[q] = MFMA_I8(A[ks], b, acc[q]);
        }
    } else {
      // ---- quarter-gated path (with agent-load watchdog) ----
      u32 spins = 0;
#pragma unroll
      for (int q4 = 0; q4 < 4; ++q4) {
        const u64 need = 0xFFFFull << (q4 * 16);
        while ((rb & need) != need) {
          u32 v = (++spins > (1u << 20)) ? ald32((const u32*)mypoll) : *mypoll;
          rb = __ballot(v >= (u32)tau);
        }
        CBAR();
        L1INV();
#pragma unroll
        for (int k4 = 0; k4 < 4; ++k4)
          A[q4 * 4 + k4] = *(const i32x4*)(ab + (size_t)(q4 * 4 + k4) * 1024);
        if (q4 > 0) {
#pragma unroll
          for (int k4 = 0; k4 < 4; ++k4) {
            const int ks = (q4 - 1) * 4 + k4;
#pragma unroll
            for (int q = 0; q < 4; ++q) {
              i32x4 b = *(const i32x4*)&wh[(size_t)(((w * 4 + q) * 16 + ks) * 64 + lane) * 16];
              acc[q] = MFMA_I8(A[ks], b, acc[q]);
            }
          }
        }
      }
#pragma unroll
      for (int k4 = 0; k4 < 4; ++k4) {
        const int ks = 12 + k4;
#pragma unroll
        for (int q = 0; q < 4; ++q) {
          i32x4 b = *(const i32x4*)&wh[(size_t)(((w * 4 + q) * 16 + ks) * 64 + lane) * 16];
          acc[q] = MFMA_I8(A[ks], b, acc[q]);
        }
      }
    }
    // ---- recombine hi/lo, gates (exp2 form), cell state, direct publish ----
    u8* dstT = pubbase + (size_t)((t & 1) * 16384);
#pragma unroll
    for (int r = 0; r < 4; ++r) {
      float p[4];
#pragma unroll
      for (int q = 0; q < 4; ++q) {
        float hiF = (float)acc[q][r];
        float loF = (float)__shfl_xor(acc[q][r], 32);
        p[q] = fmaf(sA[q], fmaf(loF, 1.f / 254.f, hiF), gx[q][r]);
      }
      float iv = sigm2(p[0]), fv = sigm2(p[1]), gv = tanh2(p[2]), ov = sigm2(p[3]);
      float cn = fv * cs[r] + iv * gv;
      cs[r] = cn;
      float h = ov * tanh2(cn * L2E2);
      float hq = h * 127.f;
      float hi = rintf(hq);
      float lo = rintf((hq - hi) * 254.f);
      if (kgrp < 2) {
        const int rr = kgrp * 4 + r;
        dstT[rr * 16 + l15] = (u8)(signed char)(int)hi;          // hi rows 0-7
        dstT[rr * 16 + 128 + l15] = (u8)(signed char)(int)lo;    // lo rows 8-15
      }
    }
    VMWAIT0();            // h byte-stores acked at L2 before tag release
    if (lane == 0) st32_plain(mytag, (u32)t);
    ((volatile u32*)flg)[2 + w] = (u32)t;
  }

  // ================= FC epilogue (h_512 = himg parity 0) =================
  {
    u32 spins = 0;
    u64 rb = __ballot(*mypoll >= (u32)SEQ);
    while (rb != ~0ull) {
      u32 v = (++spins > (1u << 20)) ? ald32((const u32*)mypoll) : *mypoll;
      rb = __ballot(v >= (u32)SEQ);
    }
  }
  CBAR();
  L1INV();
  {
    const int row = tid >> 4, c16 = tid & 15;   // tid 0-127: rows 0-7
    const int ocol = slot * 16 + c16;
    const float* wr = fcw + (size_t)ocol * 1024;
    float acc = fcb[ocol];
    const float C1 = 1.f / 127.f, C2 = 1.f / 32258.f;
    for (int ks = 0; ks < 16; ++ks) {
#pragma unroll
      for (int kg = 0; kg < 4; ++kg) {
        union { i32x4 v; signed char b[16]; } H, L;
        H.v = *(const i32x4*)(himg + (size_t)((ks * 64 + kg * 16 + row) * 16));
        L.v = *(const i32x4*)(himg + (size_t)((ks * 64 + kg * 16 + 8 + row) * 16));
        const float* wp = wr + ks * 64 + kg * 16;
#pragma unroll
        for (int j = 0; j < 16; ++j)
          acc += ((float)H.b[j] * C1 + (float)L.b[j] * C2) * wp[j];
      }
    }
    out[(size_t)(g * 8 + row) * 512 + ocol] = acc;
  }
}

// ---------- launch ----------
extern "C" void kernel_launch(void* const* d_in, const int* in_sizes, int n_in,
                              void* d_out, int out_size, void* d_ws, size_t ws_size,
                              hipStream_t stream) {
  const float* x  = (const float*)d_in[0];
  const float* W0 = (const float*)d_in[1];
  const float* W1 = (const float*)d_in[2];
  const float* W2 = (const float*)d_in[3];
  const float* W3 = (const float*)d_in[4];
  const float* bi = (const float*)d_in[5];
  const float* bf = (const float*)d_in[6];
  const float* bc = (const float*)d_in[7];
  const float* bo = (const float*)d_in[8];
  const float* fcw = (const float*)d_in[9];
  const float* fcb = (const float*)d_in[10];
  float* out = (float*)d_out;

  char* ws = (char*)d_ws;
  pack_xq<<<dim3(32768), dim3(64), 0, stream>>>(x, (u8*)(ws + OFF_XBQ),
                                                (float*)(ws + OFF_SXG));
  calc_scales<<<dim3(32), dim3(256), 0, stream>>>(W0, W1, W2, W3, (float*)(ws + OFF_SCL));
  pack_whq<<<dim3(1024), dim3(256), 0, stream>>>(W0, W1, W2, W3,
                                                 (const float*)(ws + OFF_SCL),
                                                 (u8*)(ws + OFF_WHQ));
  pack_wxq<<<dim3(512), dim3(256), 0, stream>>>(W0, W1, W2, W3,
                                                (const float*)(ws + OFF_SCL),
                                                (u8*)(ws + OFF_WXQ));
  // zero himg + tags + ctl (contiguous span through OFF_CTL+512)
  hipMemsetAsync(ws + OFF_HIMG, 0, 262144 + 32768 + 1024, stream);
  lstm_main<<<dim3(256), dim3(192), 0, stream>>>(ws, bi, bf, bc, bo, fcw, fcb, out);
}